// Round 1
// baseline (244.544 us; speedup 1.0000x reference)
//
#include <hip/hip_runtime.h>
#include <math.h>

// MemN2N encoder, eval mode.
// story: (M=256, B=16, S=64) int32; C: (4, 50257, 128) fp32; out: (16, 128) fp32.
//
// Insight 1: E_h[b,m,:] = sum_s C[h][story[m,b,s]] is independent of u ->
//            precompute once for h=1..3 (E_0 never needed, see below).
// Insight 2: u starts at 0 -> hop-0 logits are exactly 0 -> softmax exactly
//            uniform -> o_0 = mean_m E_1[b,m,:]. C[0] is dead weight.

#define NVOCAB 50257
#define EMB    128
#define NMEM   256
#define NB     16
#define SLEN   64

// E[h-1][b][m][d] for h in {1,2,3}: 3*16*256*128 floats = 6 MB.
// Device global (not d_ws) so we don't depend on ws_size; fully rewritten
// every call, so no cross-call state dependence.
__device__ float g_E[3ull * NB * NMEM * EMB];

// ---------------------------------------------------------------------------
// Kernel 1: gather + sentence-sum for tables 1..3.
// One wave (64 lanes) per (b,m) unit; each lane owns 2 emb dims (float2).
// Per token: 3 coalesced 512B row reads (one per table).
// Grid: 4096 units / 4 waves per block = 1024 blocks x 256 threads.
// ---------------------------------------------------------------------------
__global__ __launch_bounds__(256) void embed_sum_kernel(
    const int* __restrict__ story,   // [M][B][S] flat: (m*16+b)*64 + s
    const float* __restrict__ C)     // [4][VOCAB][EMB]
{
    __shared__ int toks[256];
    const int t = threadIdx.x;
    // Block's 4 units are consecutive -> their 4*64 tokens are contiguous.
    toks[t] = story[blockIdx.x * 256 + t];
    __syncthreads();

    const int wave = t >> 6;
    const int lane = t & 63;
    const int unit = blockIdx.x * 4 + wave;   // unit = m*NB + b
    const int m = unit >> 4;
    const int b = unit & 15;

    const size_t TBL = (size_t)NVOCAB * EMB;
    const float* __restrict__ C1 = C + TBL;
    const float* __restrict__ C2 = C + 2 * TBL;
    const float* __restrict__ C3 = C + 3 * TBL;
    const int dofs = lane * 2;

    float2 a1 = {0.f, 0.f}, a2 = {0.f, 0.f}, a3 = {0.f, 0.f};
    #pragma unroll 8
    for (int i = 0; i < SLEN; ++i) {
        const int tok = toks[wave * 64 + i];        // LDS broadcast
        const size_t off = (size_t)tok * EMB + dofs;
        const float2 v1 = *(const float2*)(C1 + off);
        const float2 v2 = *(const float2*)(C2 + off);
        const float2 v3 = *(const float2*)(C3 + off);
        a1.x += v1.x; a1.y += v1.y;
        a2.x += v2.x; a2.y += v2.y;
        a3.x += v3.x; a3.y += v3.y;
    }

    const size_t HS = (size_t)NB * NMEM * EMB;      // one table of E
    const size_t eoff = ((size_t)b * NMEM + m) * EMB + dofs;
    *(float2*)(g_E + eoff)          = a1;
    *(float2*)(g_E + HS + eoff)     = a2;
    *(float2*)(g_E + 2 * HS + eoff) = a3;
}

// ---------------------------------------------------------------------------
// Kernel 2: the 3-hop attention loop. One block per batch element.
// Hop 0 is the exact uniform-softmax shortcut (u=0 initially).
// ---------------------------------------------------------------------------
__global__ __launch_bounds__(256) void hops_kernel(float* __restrict__ out)
{
    const int b = blockIdx.x;
    const int t = threadIdx.x;
    const int lane = t & 63;
    const int wave = t >> 6;
    const int d = t & 127;
    const int half = t >> 7;

    __shared__ float u[EMB];
    __shared__ float prob[NMEM];
    __shared__ float part[2][EMB];
    __shared__ float red[8];

    const size_t HS = (size_t)NB * NMEM * EMB;
    const float* __restrict__ Eb = g_E + (size_t)b * NMEM * EMB;  // E_1[b]

    // ---- hop 0: u = (1/256) * sum_m E_1[b,m,:] ----
    {
        float acc = 0.f;
        const float* p = Eb + (size_t)half * 128 * EMB + d;
        #pragma unroll 4
        for (int mm = 0; mm < 128; ++mm) acc += p[(size_t)mm * EMB];
        part[half][d] = acc;
        __syncthreads();
        if (t < EMB) u[t] = (part[0][t] + part[1][t]) * (1.0f / 256.0f);
        __syncthreads();
    }

    // ---- hops 1,2: attention with E_hop, output with E_{hop+1} ----
    for (int hop = 1; hop <= 2; ++hop) {
        const float* __restrict__ EA = Eb + (size_t)(hop - 1) * HS;
        const float* __restrict__ EC = EA + HS;

        // logits[m] = dot(EA[m], u): one wave per m, lane covers 2 dims
        for (int mi = wave; mi < NMEM; mi += 4) {
            const float* row = EA + (size_t)mi * EMB;
            float v = row[lane] * u[lane] + row[lane + 64] * u[lane + 64];
            #pragma unroll
            for (int o = 32; o >= 1; o >>= 1) v += __shfl_xor(v, o);
            if (lane == 0) prob[mi] = v;
        }
        __syncthreads();

        // softmax over 256 memories
        const float x = prob[t];
        float mx = x;
        #pragma unroll
        for (int o = 32; o >= 1; o >>= 1) mx = fmaxf(mx, __shfl_xor(mx, o));
        if (lane == 0) red[wave] = mx;
        __syncthreads();
        mx = fmaxf(fmaxf(red[0], red[1]), fmaxf(red[2], red[3]));
        const float e = expf(x - mx);
        float sm = e;
        #pragma unroll
        for (int o = 32; o >= 1; o >>= 1) sm += __shfl_xor(sm, o);
        if (lane == 0) red[4 + wave] = sm;
        __syncthreads();
        const float inv = 1.0f / (red[4] + red[5] + red[6] + red[7]);
        prob[t] = e * inv;
        __syncthreads();

        // o[d] = sum_m prob[m] * EC[m,d]; u += o
        float oacc = 0.f;
        const float* p = EC + (size_t)half * 128 * EMB + d;
        #pragma unroll 4
        for (int mm = 0; mm < 128; ++mm)
            oacc += prob[half * 128 + mm] * p[(size_t)mm * EMB];
        part[half][d] = oacc;
        __syncthreads();
        if (t < EMB) u[t] += part[0][t] + part[1][t];
        __syncthreads();
    }

    if (t < EMB) out[b * EMB + t] = u[t];
}

extern "C" void kernel_launch(void* const* d_in, const int* in_sizes, int n_in,
                              void* d_out, int out_size, void* d_ws, size_t ws_size,
                              hipStream_t stream) {
    const int* story = (const int*)d_in[0];     // (256,16,64) int32
    const float* C = (const float*)d_in[1];     // (4,50257,128) fp32
    float* out = (float*)d_out;                 // (16,128) fp32

    embed_sum_kernel<<<1024, 256, 0, stream>>>(story, C);
    hops_kernel<<<NB, 256, 0, stream>>>(out);
}